// Round 2
// baseline (15670.651 us; speedup 1.0000x reference)
//
#include <hip/hip_runtime.h>

// TimeframeEncoder: 2-layer GRU-ish recurrence (SEQ=512) + final LayerNorm.
// R2: 16 blocks x 16 batch rows, 512 threads (8 waves, __launch_bounds__(512,2)
// -> 256 VGPR). Each wave owns 32 output cols (2 N-tiles per phase): halves the
// LDS A-frag replication vs 16 waves and doubles the VGPR budget so the
// per-phase B loads from L2 stay pipelined. P3 weights pinned in registers.
// x[t+1] prefetched into double-buffered LDS slot; 4 barriers/step.

#define HID 256
#define SEQL 512
#define IDIM 64

typedef __bf16 bf16x8 __attribute__((ext_vector_type(8)));
typedef float f32x4 __attribute__((ext_vector_type(4)));

__device__ __forceinline__ unsigned short f2bf(float f) {
  unsigned int u = __builtin_bit_cast(unsigned int, f);
  u += 0x7fffu + ((u >> 16) & 1u);   // RNE; values are finite here
  return (unsigned short)(u >> 16);
}
__device__ __forceinline__ float sigm(float x) { return 1.0f / (1.0f + __expf(-x)); }
__device__ __forceinline__ float tanh_(float x) { return 1.0f - 2.0f / (__expf(2.0f * x) + 1.0f); }
__device__ __forceinline__ float sanit(float v) {
  if (!(v == v)) return 0.f;
  if (isinf(v)) return v > 0.f ? 10.f : -10.f;
  return v;
}

// ---------------------------------------------------------------------------
// Weight prep (unchanged layout from R1): used fp32 weight cols -> bf16
// B-fragments. B-frag for mfma_f32_16x16x32_bf16: lane L holds
// B[k=(L>>4)*8+j][n=L&15], j<8. Tile (nt,kt) = 512 ushort.
//   Wz0p: (nt<32, kt<10) at (nt*10+kt)*512
//   Wc0p: tile base 320, (nt<16, kt<10)
//   Wz1p: tile base 480, (nt<32, kt<16)
//   Wc1p: tile base 992, (nt<16, kt<16)
// ---------------------------------------------------------------------------
__global__ __launch_bounds__(256) void prep_weights(
    const float* __restrict__ Wz0, const float* __restrict__ Wc0,
    const float* __restrict__ Wz1, const float* __restrict__ Wc1,
    unsigned short* __restrict__ ws) {
  int idx = blockIdx.x * 256 + threadIdx.x;  // 638976 threads
  const float* W;
  int stride, KT, base;
  if (idx < 163840)      { W = Wz0; stride = 768; KT = 10; base = 0; }
  else if (idx < 245760) { W = Wc0; stride = 256; KT = 10; base = 163840; idx -= 163840; }
  else if (idx < 507904) { W = Wz1; stride = 768; KT = 16; base = 245760; idx -= 245760; }
  else                   { W = Wc1; stride = 256; KT = 16; base = 507904; idx -= 507904; }
  int tile = idx >> 9;
  int t = idx & 511;
  int nt = tile / KT;
  int kt = tile - nt * KT;
  int n15 = t & 15;
  int klocal = t >> 4;
  int k = (kt << 5) + klocal;
  int n = (nt << 4) + n15;
  int lane = ((klocal >> 3) << 4) | n15;
  int j = klocal & 7;
  ws[base + (tile << 9) + (lane << 3) + j] = f2bf(W[k * stride + n]);
}

// ---------------------------------------------------------------------------
// Main recurrent kernel: grid 16 x 512 threads (8 waves).
// Wave w owns cols colz0=32w+l15 and colz1=colz0+16 for z/r/htilde/h (both
// layers) -> z, r*h pair with this thread's own fp32 h registers.
// LDS: A0[8kt] A0r[8kt] xbuf[2][2kt] A1[16kt] A1r[16kt]  (52 KB)
// ---------------------------------------------------------------------------
__global__ __launch_bounds__(512, 2) void gru_main(
    const float* __restrict__ x,
    const float* __restrict__ bz0, const float* __restrict__ bc0,
    const float* __restrict__ bz1, const float* __restrict__ bc1,
    const float* __restrict__ gamma, const float* __restrict__ beta,
    const unsigned short* __restrict__ wsw,
    float* __restrict__ out) {
  __shared__ __align__(16) unsigned char lds[53248];
  unsigned short* A0   = (unsigned short*)lds;  // combined0 h-part, 8 kt
  unsigned short* A0r  = A0 + 4096;             // reset0 h-part, 8 kt
  unsigned short* xbuf = A0 + 8192;             // x frags, 2 bufs x 2 kt
  unsigned short* A1   = A0 + 10240;            // combined1 [h1|h0], 16 kt
  unsigned short* A1r  = A0 + 18432;            // reset1 [r1*h1|h0], 16 kt

  const int tid  = threadIdx.x;
  const int wave = tid >> 6;   // 0..7
  const int lane = tid & 63;
  const int l15  = lane & 15;
  const int quad = lane >> 4;
  const int row0 = blockIdx.x << 4;

  // zero h-parts read at t=0 (A0 kt0-7, A1 kt0-7)
  for (int i = tid; i < 4096; i += 512) { A0[i] = 0; A1[i] = 0; }

  const int colz0 = (wave << 5) | l15;
  const int colz1 = colz0 + 16;
  // owned C/D element (m=quad*4+i, col) -> frag ushort index (+i*8 per i)
  #define DLOC(c) ((((c) >> 5) << 9) + (((((c) >> 3) & 3) << 4) + (quad << 2)) * 8 + ((c) & 7))
  const int dlo0 = DLOC(colz0), dlo1 = DLOC(colz1);
  const int dhi0 = dlo0 + 4096, dhi1 = dlo1 + 4096;  // same elem at k+=256 (8 kt later)

  // biases (regs, direct from global)
  const float bz0z0 = bz0[colz0], bz0z1 = bz0[colz1];
  const float bz0r0 = bz0[256 + colz0], bz0r1 = bz0[256 + colz1];
  const float bc0c0 = bc0[colz0], bc0c1 = bc0[colz1];
  const float bz1z0 = bz1[colz0], bz1z1 = bz1[colz1];
  const float bz1r0 = bz1[256 + colz0], bz1r1 = bz1[256 + colz1];
  const float bc1c0 = bc1[colz0], bc1c1 = bc1[colz1];

  const bf16x8* __restrict__ wsv = (const bf16x8*)wsw;
  const int nt0 = 2 * wave, nt1 = 2 * wave + 1;
  const int zb0 = (nt0 * 10) * 64 + lane,        zb1 = (nt1 * 10) * 64 + lane;
  const int rb0 = ((16 + nt0) * 10) * 64 + lane, rb1 = ((17 + nt0) * 10) * 64 + lane;
  const int z1b0 = (480 + nt0 * 16) * 64 + lane, z1b1 = (480 + nt1 * 16) * 64 + lane;
  const int r1b0 = (480 + (16 + nt0) * 16) * 64 + lane, r1b1 = (480 + (17 + nt0) * 16) * 64 + lane;
  const int c1b0 = (992 + nt0 * 16) * 64 + lane, c1b1 = (992 + nt1 * 16) * 64 + lane;

  // P3 (Wc0) B tiles pinned in registers: 20 tiles = 80 VGPR
  bf16x8 b3[20];
#pragma unroll
  for (int kt = 0; kt < 10; ++kt) {
    b3[kt]      = wsv[(320 + nt0 * 10 + kt) * 64 + lane];
    b3[10 + kt] = wsv[(320 + nt1 * 10 + kt) * 64 + lane];
  }

  // x staging: thread (row=tid>>5, c2=(tid&31)*2) loads x[row][t][c2:c2+2]
  const int xrow = tid >> 5;
  const int c2 = (tid & 31) << 1;
  const float* xpf = x + (size_t)(row0 + xrow) * (SEQL * IDIM) + c2;
  const int xdst = ((c2 >> 5) << 9) + ((((c2 >> 3) & 3) << 4) | xrow) * 8 + (c2 & 7);

  { // preload x[0] into xbuf[0]
    float2 xv = *(const float2*)(xpf);
    xbuf[xdst]     = f2bf(sanit(xv.x));
    xbuf[xdst + 1] = f2bf(sanit(xv.y));
  }

  f32x4 h0a = {0,0,0,0}, h0b = {0,0,0,0};
  f32x4 h1a = {0,0,0,0}, h1b = {0,0,0,0};

  __syncthreads();

  for (int t = 0; t < SEQL; ++t) {
    const unsigned short* xb = xbuf + ((t & 1) << 10);
    // issue x[t+1] load early; consumed in P5 region
    float2 xn;
    const bool havex = (t < SEQL - 1);
    if (havex) xn = *(const float2*)(xpf + (t + 1) * IDIM);

    // ---- P2: gates0 = [h0|x] @ Wz0[:,:512] + bz0 ----
    f32x4 az0 = {bz0z0, bz0z0, bz0z0, bz0z0}, az1 = {bz0z1, bz0z1, bz0z1, bz0z1};
    f32x4 ar0 = {bz0r0, bz0r0, bz0r0, bz0r0}, ar1 = {bz0r1, bz0r1, bz0r1, bz0r1};
#pragma unroll
    for (int kt = 0; kt < 8; ++kt) {
      bf16x8 a = *(const bf16x8*)(A0 + (kt << 9) + (lane << 3));
      az0 = __builtin_amdgcn_mfma_f32_16x16x32_bf16(a, wsv[zb0 + (kt << 6)], az0, 0, 0, 0);
      az1 = __builtin_amdgcn_mfma_f32_16x16x32_bf16(a, wsv[zb1 + (kt << 6)], az1, 0, 0, 0);
      ar0 = __builtin_amdgcn_mfma_f32_16x16x32_bf16(a, wsv[rb0 + (kt << 6)], ar0, 0, 0, 0);
      ar1 = __builtin_amdgcn_mfma_f32_16x16x32_bf16(a, wsv[rb1 + (kt << 6)], ar1, 0, 0, 0);
    }
#pragma unroll
    for (int kt = 8; kt < 10; ++kt) {
      bf16x8 a = *(const bf16x8*)(xb + ((kt - 8) << 9) + (lane << 3));
      az0 = __builtin_amdgcn_mfma_f32_16x16x32_bf16(a, wsv[zb0 + (kt << 6)], az0, 0, 0, 0);
      az1 = __builtin_amdgcn_mfma_f32_16x16x32_bf16(a, wsv[zb1 + (kt << 6)], az1, 0, 0, 0);
      ar0 = __builtin_amdgcn_mfma_f32_16x16x32_bf16(a, wsv[rb0 + (kt << 6)], ar0, 0, 0, 0);
      ar1 = __builtin_amdgcn_mfma_f32_16x16x32_bf16(a, wsv[rb1 + (kt << 6)], ar1, 0, 0, 0);
    }
    float z0[8];
#pragma unroll
    for (int i = 0; i < 4; ++i) {
      z0[i]     = sigm(az0[i]);
      z0[4 + i] = sigm(az1[i]);
      A0r[dlo0 + i * 8] = f2bf(sigm(ar0[i]) * h0a[i]);
      A0r[dlo1 + i * 8] = f2bf(sigm(ar1[i]) * h0b[i]);
    }
    __syncthreads();

    // ---- P3: htilde0 = tanh([r*h0|x] @ Wc0 + bc0); h0 update ----
    f32x4 ac0 = {bc0c0, bc0c0, bc0c0, bc0c0}, ac1 = {bc0c1, bc0c1, bc0c1, bc0c1};
#pragma unroll
    for (int kt = 0; kt < 8; ++kt) {
      bf16x8 a = *(const bf16x8*)(A0r + (kt << 9) + (lane << 3));
      ac0 = __builtin_amdgcn_mfma_f32_16x16x32_bf16(a, b3[kt], ac0, 0, 0, 0);
      ac1 = __builtin_amdgcn_mfma_f32_16x16x32_bf16(a, b3[10 + kt], ac1, 0, 0, 0);
    }
#pragma unroll
    for (int kt = 8; kt < 10; ++kt) {
      bf16x8 a = *(const bf16x8*)(xb + ((kt - 8) << 9) + (lane << 3));
      ac0 = __builtin_amdgcn_mfma_f32_16x16x32_bf16(a, b3[kt], ac0, 0, 0, 0);
      ac1 = __builtin_amdgcn_mfma_f32_16x16x32_bf16(a, b3[10 + kt], ac1, 0, 0, 0);
    }
#pragma unroll
    for (int i = 0; i < 4; ++i) {
      float ht = tanh_(ac0[i]);
      float hn = h0a[i] + z0[i] * (ht - h0a[i]);
      h0a[i] = hn;
      unsigned short hb = f2bf(hn);
      A0[dlo0 + i * 8] = hb; A1[dhi0 + i * 8] = hb; A1r[dhi0 + i * 8] = hb;
      ht = tanh_(ac1[i]);
      hn = h0b[i] + z0[4 + i] * (ht - h0b[i]);
      h0b[i] = hn;
      hb = f2bf(hn);
      A0[dlo1 + i * 8] = hb; A1[dhi1 + i * 8] = hb; A1r[dhi1 + i * 8] = hb;
    }
    __syncthreads();

    // ---- P4: gates1 = [h1|h0] @ Wz1[:,:512] + bz1 ----
    f32x4 bz1za = {bz1z0, bz1z0, bz1z0, bz1z0}, bz1zb = {bz1z1, bz1z1, bz1z1, bz1z1};
    f32x4 bz1ra = {bz1r0, bz1r0, bz1r0, bz1r0}, bz1rb = {bz1r1, bz1r1, bz1r1, bz1r1};
#pragma unroll
    for (int kt = 0; kt < 16; ++kt) {
      bf16x8 a = *(const bf16x8*)(A1 + (kt << 9) + (lane << 3));
      bz1za = __builtin_amdgcn_mfma_f32_16x16x32_bf16(a, wsv[z1b0 + (kt << 6)], bz1za, 0, 0, 0);
      bz1zb = __builtin_amdgcn_mfma_f32_16x16x32_bf16(a, wsv[z1b1 + (kt << 6)], bz1zb, 0, 0, 0);
      bz1ra = __builtin_amdgcn_mfma_f32_16x16x32_bf16(a, wsv[r1b0 + (kt << 6)], bz1ra, 0, 0, 0);
      bz1rb = __builtin_amdgcn_mfma_f32_16x16x32_bf16(a, wsv[r1b1 + (kt << 6)], bz1rb, 0, 0, 0);
    }
    float z1[8];
#pragma unroll
    for (int i = 0; i < 4; ++i) {
      z1[i]     = sigm(bz1za[i]);
      z1[4 + i] = sigm(bz1zb[i]);
      A1r[dlo0 + i * 8] = f2bf(sigm(bz1ra[i]) * h1a[i]);
      A1r[dlo1 + i * 8] = f2bf(sigm(bz1rb[i]) * h1b[i]);
    }
    __syncthreads();

    // ---- P5: htilde1; h1 update; stage x[t+1] ----
    if (havex) {
      unsigned short* xb1 = xbuf + (((t + 1) & 1) << 10);
      xb1[xdst]     = f2bf(sanit(xn.x));
      xb1[xdst + 1] = f2bf(sanit(xn.y));
    }
    f32x4 ac10 = {bc1c0, bc1c0, bc1c0, bc1c0}, ac11 = {bc1c1, bc1c1, bc1c1, bc1c1};
#pragma unroll
    for (int kt = 0; kt < 16; ++kt) {
      bf16x8 a = *(const bf16x8*)(A1r + (kt << 9) + (lane << 3));
      ac10 = __builtin_amdgcn_mfma_f32_16x16x32_bf16(a, wsv[c1b0 + (kt << 6)], ac10, 0, 0, 0);
      ac11 = __builtin_amdgcn_mfma_f32_16x16x32_bf16(a, wsv[c1b1 + (kt << 6)], ac11, 0, 0, 0);
    }
#pragma unroll
    for (int i = 0; i < 4; ++i) {
      float ht = tanh_(ac10[i]);
      h1a[i] = h1a[i] + z1[i] * (ht - h1a[i]);
      A1[dlo0 + i * 8] = f2bf(h1a[i]);
      ht = tanh_(ac11[i]);
      h1b[i] = h1b[i] + z1[4 + i] * (ht - h1b[i]);
      A1[dlo1 + i * 8] = f2bf(h1b[i]);
    }
    __syncthreads();
  }

  // ---- Epilogue: LayerNorm(h1) per row ----
  float* h1buf = (float*)lds;  // 16x256 fp32 = 16 KB (frag buffers dead now)
#pragma unroll
  for (int i = 0; i < 4; ++i) {
    h1buf[((quad << 2) + i) * 256 + colz0] = h1a[i];
    h1buf[((quad << 2) + i) * 256 + colz1] = h1b[i];
  }
  __syncthreads();

  const int orow = tid >> 5;       // 16 rows, 32 lanes each
  const int oc = tid & 31;
  float v[8], s = 0.f, sq = 0.f;
#pragma unroll
  for (int j = 0; j < 8; ++j) {
    v[j] = h1buf[orow * 256 + oc + (j << 5)];
    s += v[j];
    sq += v[j] * v[j];
  }
#pragma unroll
  for (int off = 16; off > 0; off >>= 1) {   // xor<32 stays in the 32-lane group
    s  += __shfl_xor(s, off);
    sq += __shfl_xor(sq, off);
  }
  float mean = s * (1.f / 256.f);
  float var  = sq * (1.f / 256.f) - mean * mean;
  float rstd = rsqrtf(var + 1e-5f);
  float* op = out + (size_t)(row0 + orow) * 256;
#pragma unroll
  for (int j = 0; j < 8; ++j) {
    int c = oc + (j << 5);
    op[c] = (v[j] - mean) * rstd * gamma[c] + beta[c];
  }
}

extern "C" void kernel_launch(void* const* d_in, const int* in_sizes, int n_in,
                              void* d_out, int out_size, void* d_ws, size_t ws_size,
                              hipStream_t stream) {
  const float* x     = (const float*)d_in[0];
  const float* Wz0   = (const float*)d_in[1];
  const float* bz0   = (const float*)d_in[2];
  const float* Wc0   = (const float*)d_in[3];
  const float* bc0   = (const float*)d_in[4];
  const float* Wz1   = (const float*)d_in[5];
  const float* bz1   = (const float*)d_in[6];
  const float* Wc1   = (const float*)d_in[7];
  const float* bc1   = (const float*)d_in[8];
  const float* gamma = (const float*)d_in[9];
  const float* beta  = (const float*)d_in[10];
  unsigned short* ws = (unsigned short*)d_ws;
  float* out = (float*)d_out;

  hipLaunchKernelGGL(prep_weights, dim3(2496), dim3(256), 0, stream, Wz0, Wc0, Wz1, Wc1, ws);
  hipLaunchKernelGGL(gru_main, dim3(16), dim3(512), 0, stream,
                     x, bz0, bc0, bz1, bc1, gamma, beta, ws, out);
}

// Round 3
// 15132.471 us; speedup vs baseline: 1.0356x; 1.0356x over previous
//
#include <hip/hip_runtime.h>

// TimeframeEncoder: 2-layer GRU-ish recurrence (SEQ=512) + final LayerNorm.
// R3: WEIGHT-STATIONARY IN REGISTERS. 16 blocks x 16 batch rows, 1024 thr
// (16 waves, 4/SIMD, __launch_bounds__(1024,4) -> 512 VGPR/wave). Each wave
// owns 16 output cols; its 78 B-fragment tiles (312 VGPR) are loaded ONCE
// before the t-loop and reused for all 512 steps -> zero in-loop L2 weight
// traffic (R1/R2's bottleneck: ~1.1 MB/CU/step of barrier-fenced L2 reads).
// In-loop traffic is LDS A-frags only (~832 KB/CU/step) + x from HBM.

#define HID 256
#define SEQL 512
#define IDIM 64

typedef __bf16 bf16x8 __attribute__((ext_vector_type(8)));
typedef float f32x4 __attribute__((ext_vector_type(4)));

__device__ __forceinline__ unsigned short f2bf(float f) {
  unsigned int u = __builtin_bit_cast(unsigned int, f);
  u += 0x7fffu + ((u >> 16) & 1u);   // RNE; values are finite here
  return (unsigned short)(u >> 16);
}
__device__ __forceinline__ float sigm(float x) { return 1.0f / (1.0f + __expf(-x)); }
__device__ __forceinline__ float tanh_(float x) { return 1.0f - 2.0f / (__expf(2.0f * x) + 1.0f); }
__device__ __forceinline__ float sanit(float v) {
  if (!(v == v)) return 0.f;
  if (isinf(v)) return v > 0.f ? 10.f : -10.f;
  return v;
}

// ---------------------------------------------------------------------------
// Weight prep (layout verified in R1/R2): used fp32 weight cols -> bf16
// B-fragments. B-frag for mfma_f32_16x16x32_bf16: lane L holds
// B[k=(L>>4)*8+j][n=L&15], j<8. Tile (nt,kt) = 512 ushort, [lane][j].
//   Wz0p: (nt<32, kt<10) at tile (nt*10+kt)
//   Wc0p: tile base 320, (nt<16, kt<10)
//   Wz1p: tile base 480, (nt<32, kt<16)
//   Wc1p: tile base 992, (nt<16, kt<16)
// ---------------------------------------------------------------------------
__global__ __launch_bounds__(256) void prep_weights(
    const float* __restrict__ Wz0, const float* __restrict__ Wc0,
    const float* __restrict__ Wz1, const float* __restrict__ Wc1,
    unsigned short* __restrict__ ws) {
  int idx = blockIdx.x * 256 + threadIdx.x;  // 638976 threads
  const float* W;
  int stride, KT, base;
  if (idx < 163840)      { W = Wz0; stride = 768; KT = 10; base = 0; }
  else if (idx < 245760) { W = Wc0; stride = 256; KT = 10; base = 163840; idx -= 163840; }
  else if (idx < 507904) { W = Wz1; stride = 768; KT = 16; base = 245760; idx -= 245760; }
  else                   { W = Wc1; stride = 256; KT = 16; base = 507904; idx -= 507904; }
  int tile = idx >> 9;
  int t = idx & 511;
  int nt = tile / KT;
  int kt = tile - nt * KT;
  int n15 = t & 15;
  int klocal = t >> 4;
  int k = (kt << 5) + klocal;
  int n = (nt << 4) + n15;
  int lane = ((klocal >> 3) << 4) | n15;
  int j = klocal & 7;
  ws[base + (tile << 9) + (lane << 3) + j] = f2bf(W[k * stride + n]);
}

// ---------------------------------------------------------------------------
// Main recurrent kernel: grid 16 x 1024 threads (16 waves, 1 block/CU).
// Wave w owns cols [16w,16w+16) of z/htilde/h (both layers) and r-cols
// 256+[16w,16w+16) -> z and r*h pair with this thread's own fp32 h regs.
// LDS (ushort units): A0[0..4096) h0-part 8kt | A0r[4096..8192) 8kt |
//   A1[8192..16384) [h1|h0] 16kt | A1r[16384..24576) 16kt |
//   xbuf[24576..26624) 2 bufs x 2kt.   53,248 B total.
// ---------------------------------------------------------------------------
__global__ __launch_bounds__(1024, 4) void gru_main(
    const float* __restrict__ x,
    const float* __restrict__ bz0, const float* __restrict__ bc0,
    const float* __restrict__ bz1, const float* __restrict__ bc1,
    const float* __restrict__ gamma, const float* __restrict__ beta,
    const unsigned short* __restrict__ wsw,
    float* __restrict__ out) {
  __shared__ __align__(16) unsigned short lds[26624];
  unsigned short* A0   = lds;
  unsigned short* A0r  = lds + 4096;
  unsigned short* A1   = lds + 8192;
  unsigned short* A1r  = lds + 16384;
  unsigned short* xbuf = lds + 24576;

  const int tid  = threadIdx.x;
  const int wave = tid >> 6;   // 0..15
  const int lane = tid & 63;
  const int l15  = lane & 15;
  const int quad = lane >> 4;
  const int row0 = blockIdx.x << 4;

  // zero the h-parts read at t=0 (A0 all, A1 h1-part kt0-7)
  for (int i = tid; i < 4096; i += 1024) { A0[i] = 0; A1[i] = 0; }

  const int colz = (wave << 4) | l15;
  // owned C/D element (m=quad*4+i, col=colz) -> A-frag ushort index (+i*8)
  const int dlo = ((colz >> 5) << 9) + ((((colz >> 3) & 3) << 4) + (quad << 2)) * 8 + (colz & 7);
  const int dhi = dlo + 4096;  // same element at k += 256 (8 kt further)

  // biases to regs
  const float bz0z = bz0[colz], bz0r = bz0[256 + colz];
  const float bc0c = bc0[colz];
  const float bz1z = bz1[colz], bz1r = bz1[256 + colz];
  const float bc1c = bc1[colz];

  const bf16x8* __restrict__ wsv = (const bf16x8*)wsw;

  // ---- Stationary B tiles: 78 tiles = 312 VGPR/lane, loaded once ----
  bf16x8 b2z[10], b2r[10], b3c[10], b4z[16], b4r[16], b5c[16];
#pragma unroll
  for (int kt = 0; kt < 10; ++kt) {
    b2z[kt] = wsv[(wave * 10 + kt) * 64 + lane];
    b2r[kt] = wsv[((16 + wave) * 10 + kt) * 64 + lane];
    b3c[kt] = wsv[(320 + wave * 10 + kt) * 64 + lane];
  }
#pragma unroll
  for (int kt = 0; kt < 16; ++kt) {
    b4z[kt] = wsv[(480 + wave * 16 + kt) * 64 + lane];
    b4r[kt] = wsv[(480 + (16 + wave) * 16 + kt) * 64 + lane];
    b5c[kt] = wsv[(992 + wave * 16 + kt) * 64 + lane];
  }

  // x staging: thread (row=wave, chan=lane) loads x[row0+wave][t][lane]
  const float* xp = x + (size_t)(row0 + wave) * (SEQL * IDIM) + lane;
  const int xdst = ((lane >> 5) << 9) + ((((lane >> 3) & 3) << 4) + wave) * 8 + (lane & 7);
  xbuf[xdst] = f2bf(sanit(xp[0]));   // x[0] -> buffer 0

  f32x4 h0 = {0.f, 0.f, 0.f, 0.f};
  f32x4 h1 = {0.f, 0.f, 0.f, 0.f};

  __syncthreads();

  for (int t = 0; t < SEQL; ++t) {
    const unsigned short* xb = xbuf + ((t & 1) << 10);
    const bool havex = (t < SEQL - 1);
    float xn;
    if (havex) xn = xp[(t + 1) * IDIM];   // prefetch; stored in P5

    // ---- P2: gates0 = [h0|x] @ Wz0[:,:512] + bz0 ----
    f32x4 az = {bz0z, bz0z, bz0z, bz0z};
    f32x4 ar = {bz0r, bz0r, bz0r, bz0r};
#pragma unroll
    for (int kt = 0; kt < 8; ++kt) {
      bf16x8 a = *(const bf16x8*)(A0 + (kt << 9) + (lane << 3));
      az = __builtin_amdgcn_mfma_f32_16x16x32_bf16(a, b2z[kt], az, 0, 0, 0);
      ar = __builtin_amdgcn_mfma_f32_16x16x32_bf16(a, b2r[kt], ar, 0, 0, 0);
    }
#pragma unroll
    for (int kt = 8; kt < 10; ++kt) {
      bf16x8 a = *(const bf16x8*)(xb + ((kt - 8) << 9) + (lane << 3));
      az = __builtin_amdgcn_mfma_f32_16x16x32_bf16(a, b2z[kt], az, 0, 0, 0);
      ar = __builtin_amdgcn_mfma_f32_16x16x32_bf16(a, b2r[kt], ar, 0, 0, 0);
    }
    float z0[4];
#pragma unroll
    for (int i = 0; i < 4; ++i) {
      z0[i] = sigm(az[i]);
      A0r[dlo + i * 8] = f2bf(sigm(ar[i]) * h0[i]);
    }
    __syncthreads();

    // ---- P3: htilde0 = tanh([r*h0|x] @ Wc0 + bc0); h0 update ----
    f32x4 ac = {bc0c, bc0c, bc0c, bc0c};
#pragma unroll
    for (int kt = 0; kt < 8; ++kt) {
      bf16x8 a = *(const bf16x8*)(A0r + (kt << 9) + (lane << 3));
      ac = __builtin_amdgcn_mfma_f32_16x16x32_bf16(a, b3c[kt], ac, 0, 0, 0);
    }
#pragma unroll
    for (int kt = 8; kt < 10; ++kt) {
      bf16x8 a = *(const bf16x8*)(xb + ((kt - 8) << 9) + (lane << 3));
      ac = __builtin_amdgcn_mfma_f32_16x16x32_bf16(a, b3c[kt], ac, 0, 0, 0);
    }
#pragma unroll
    for (int i = 0; i < 4; ++i) {
      float ht = tanh_(ac[i]);
      float hn = h0[i] + z0[i] * (ht - h0[i]);
      h0[i] = hn;
      unsigned short hb = f2bf(hn);
      A0[dlo + i * 8]  = hb;   // next step's combined0 h-part
      A1[dhi + i * 8]  = hb;   // combined1 h0-part (k=256+colz)
      A1r[dhi + i * 8] = hb;   // reset1 h0-part
    }
    __syncthreads();

    // ---- P4: gates1 = [h1|h0] @ Wz1[:,:512] + bz1 ----
    f32x4 az1 = {bz1z, bz1z, bz1z, bz1z};
    f32x4 ar1 = {bz1r, bz1r, bz1r, bz1r};
#pragma unroll
    for (int kt = 0; kt < 16; ++kt) {
      bf16x8 a = *(const bf16x8*)(A1 + (kt << 9) + (lane << 3));
      az1 = __builtin_amdgcn_mfma_f32_16x16x32_bf16(a, b4z[kt], az1, 0, 0, 0);
      ar1 = __builtin_amdgcn_mfma_f32_16x16x32_bf16(a, b4r[kt], ar1, 0, 0, 0);
    }
    float z1[4];
#pragma unroll
    for (int i = 0; i < 4; ++i) {
      z1[i] = sigm(az1[i]);
      A1r[dlo + i * 8] = f2bf(sigm(ar1[i]) * h1[i]);
    }
    __syncthreads();

    // ---- P5: htilde1; h1 update; stage x[t+1] ----
    if (havex) {
      unsigned short* xb1 = xbuf + (((t + 1) & 1) << 10);
      xb1[xdst] = f2bf(sanit(xn));
    }
    f32x4 ac1 = {bc1c, bc1c, bc1c, bc1c};
#pragma unroll
    for (int kt = 0; kt < 16; ++kt) {
      bf16x8 a = *(const bf16x8*)(A1r + (kt << 9) + (lane << 3));
      ac1 = __builtin_amdgcn_mfma_f32_16x16x32_bf16(a, b5c[kt], ac1, 0, 0, 0);
    }
#pragma unroll
    for (int i = 0; i < 4; ++i) {
      float ht = tanh_(ac1[i]);
      h1[i] = h1[i] + z1[i] * (ht - h1[i]);
      A1[dlo + i * 8] = f2bf(h1[i]);   // next step's combined1 h1-part
    }
    __syncthreads();
  }

  // ---- Epilogue: LayerNorm(h1) per row ----
  float* h1buf = (float*)lds;  // frag buffers dead; 16x256 fp32 = 16 KB
#pragma unroll
  for (int i = 0; i < 4; ++i) h1buf[((quad << 2) + i) * 256 + colz] = h1[i];
  __syncthreads();

  float v[4], s = 0.f, sq = 0.f;
#pragma unroll
  for (int j = 0; j < 4; ++j) {
    v[j] = h1buf[wave * 256 + lane + (j << 6)];
    s += v[j];
    sq += v[j] * v[j];
  }
#pragma unroll
  for (int off = 32; off > 0; off >>= 1) {
    s  += __shfl_xor(s, off);
    sq += __shfl_xor(sq, off);
  }
  float mean = s * (1.f / 256.f);
  float var  = sq * (1.f / 256.f) - mean * mean;   // population var (jnp.var)
  float rstd = rsqrtf(var + 1e-5f);
  float* op = out + (size_t)(row0 + wave) * 256;
#pragma unroll
  for (int j = 0; j < 4; ++j) {
    int c = lane + (j << 6);
    op[c] = (v[j] - mean) * rstd * gamma[c] + beta[c];
  }
}

extern "C" void kernel_launch(void* const* d_in, const int* in_sizes, int n_in,
                              void* d_out, int out_size, void* d_ws, size_t ws_size,
                              hipStream_t stream) {
  const float* x     = (const float*)d_in[0];
  const float* Wz0   = (const float*)d_in[1];
  const float* bz0   = (const float*)d_in[2];
  const float* Wc0   = (const float*)d_in[3];
  const float* bc0   = (const float*)d_in[4];
  const float* Wz1   = (const float*)d_in[5];
  const float* bz1   = (const float*)d_in[6];
  const float* Wc1   = (const float*)d_in[7];
  const float* bc1   = (const float*)d_in[8];
  const float* gamma = (const float*)d_in[9];
  const float* beta  = (const float*)d_in[10];
  unsigned short* ws = (unsigned short*)d_ws;
  float* out = (float*)d_out;

  hipLaunchKernelGGL(prep_weights, dim3(2496), dim3(256), 0, stream, Wz0, Wc0, Wz1, Wc1, ws);
  hipLaunchKernelGGL(gru_main, dim3(16), dim3(1024), 0, stream,
                     x, bz0, bc0, bz1, bc1, gamma, beta, ws, out);
}